// Round 6
// baseline (100.046 us; speedup 1.0000x reference)
//
#include <hip/hip_runtime.h>

#define NPAIR 8192   // B*NCG

// ===================== config-deduplicated path =====================
// Node layer-1 output depends only on (c, i, f_s0, op_s0, f_s1, op_s1):
// 5292 real configs + 4 init pseudo-rows = 5296. config_kernel builds
// tab[cfg] = relu(y1_cfg) @ W2; gather_kernel is a pure gather/aggregate.
// R14: scalar/compile-time-indexed accumulators only (runtime-indexed
//   register arrays spill to scratch).
// R15: cooperative fusion FAILED (235us). NEVER use cooperative launch here.
// R16 FAILED (127us): narrow strided global loads latency-exposed.
// R17 (104us): stage ALL weights at t0 (one ~86KB burst), fuse s1|at1|at2.
// R18 (100.8us): 512 thr; step 3 was LDS-BW-bound (LDS BW is per-CU).
// R19 (98.3us): 2-D register blocking + b128 LDS reads everywhere.
// Budget model (fits R0/R15/R17/R18/R19): ~82us = 2 harness poison-fills
//   (in timed window, uncontrollable) + config (~9) + gather (~6) + gaps.
// R20: (a) at1/at2 depend only on staged weights -> run them concurrently
//   with y0 (region A); s1 alone in region B. Same 4 barriers, better
//   balance. (b) gather: 512 blocks x 16 pairs (R15-phase-2-verified loop),
//   arch staging amortized, S0/S1 hoisted (P&1 == pp&1).
#define NCFG_REAL 5292
#define NCFG      5296
#define CPER      2646
#define NBLK      221       // <= 256: single wave of blocks, no tail round
#define WS_AT2F   0         // at2 table [7][128] (row 0 zeroed)
#define WS_TAB    1024      // tab [NCFG][128]
#define WS_NEED   ((size_t)(1024 + NCFG * 128) * 4)

#define COMP4(v, j) ((j) == 0 ? (v).x : (j) == 1 ? (v).y : (j) == 2 ? (v).z : (v).w)

__device__ __forceinline__ float sigmoidf_(float x) {
  return 1.0f / (1.0f + __expf(-x));
}

// 221 blocks x 512 threads; 24 configs per block, 3 per wave.
__global__ __launch_bounds__(512) void config_kernel(
    const float* __restrict__ init_emb, const float* __restrict__ other_emb,
    const float* __restrict__ op_embs,  const float* __restrict__ Wx,
    const float* __restrict__ bx,       const float* __restrict__ W1,
    const float* __restrict__ Wa1,      const float* __restrict__ ba1,
    const float* __restrict__ W2,       const float* __restrict__ Wa2,
    const float* __restrict__ ba2,      float* __restrict__ ws)
{
  __shared__ __align__(16) float wx_sh[2304];   // Wx 48x48
  __shared__ __align__(16) float w1_sh[6144];   // W1 48x128
  __shared__ __align__(16) float wa1sh[6144];   // Wa1 48x128; later y1 overlay
  __shared__ __align__(16) float wa2sh[6144];   // Wa2 48x128
  __shared__ __align__(16) float s1sh[1536];    // support1 [2][6][128]
  __shared__ __align__(16) float at1sh[896];    // sigmoid(a1) [7][128] row0=0
  __shared__ __align__(16) float at2sh[896];    // sigmoid(a2) [7][128] row0=0
  __shared__ __align__(16) float y0sh[576];     // y0 [2][6][48]
  __shared__ __align__(16) float embsh[336];    // init(192) other(96) bx(48)
  __shared__ __align__(16) float opsh[336];     // op_embs [7][48]
  const int t = threadIdx.x;

  // ---- step 1: stage EVERYTHING (one wide burst, single wait) ----
  for (int i = t; i < 576; i += 512)  ((float4*)wx_sh)[i] = ((const float4*)Wx)[i];
  for (int i = t; i < 1536; i += 512) ((float4*)w1_sh)[i] = ((const float4*)W1)[i];
  for (int i = t; i < 1536; i += 512) ((float4*)wa1sh)[i] = ((const float4*)Wa1)[i];
  for (int i = t; i < 1536; i += 512) ((float4*)wa2sh)[i] = ((const float4*)Wa2)[i];
  if (t < 48)        ((float4*)embsh)[t]     = ((const float4*)init_emb)[t];
  else if (t < 72)   ((float4*)embsh)[t]     = ((const float4*)other_emb)[t - 48];
  else if (t < 84)   ((float4*)embsh)[t]     = ((const float4*)bx)[t - 72];
  else if (t < 168)  ((float4*)opsh)[t - 84] = ((const float4*)op_embs)[t - 84];
  __syncthreads();

  // ---- region A: y0 (t<144)  ||  at1/at2 (t in [192,320))  ||  op-0 zero --
  // at1/at2 depend only on staged opsh/wa/ba -> no need to wait for y0.
  if (t < 144) {
    // y0[r][h] = node @ Wx + bx, all-b128 LDS reads. r=t/12, h4=t%12.
    const int r = t / 12, h4 = t - r * 12;
    const int c = r / 6, i = r - c * 6;
    const float* nptr = (i < 2) ? (embsh + (c * 2 + i) * 48)
                                : (embsh + 192 + c * 48);
    float4 acc = *(const float4*)(embsh + 288 + h4 * 4);   // bx
    #pragma unroll
    for (int d4 = 0; d4 < 12; ++d4) {
      float4 nv = *(const float4*)(nptr + d4 * 4);
      #pragma unroll
      for (int j = 0; j < 4; ++j) {
        float4 wv = *(const float4*)(wx_sh + (d4 * 4 + j) * 48 + h4 * 4);
        float s = COMP4(nv, j);
        acc.x += s * wv.x; acc.y += s * wv.y;
        acc.z += s * wv.z; acc.w += s * wv.w;
      }
    }
    *(float4*)(y0sh + r * 48 + h4 * 4) = acc;
  } else if (t >= 192 && t < 320) {
    // at1/at2: thread = (3 op) x (4 o). ops {1,2,3} or {4,5,6}.
    const int is2  = (t >= 256);
    const int u    = t - (is2 ? 256 : 192);
    const int half = u >> 5, o4 = (u & 31) << 2;
    const int op0_ = 1 + 3 * half;
    const float* wsh_  = is2 ? wa2sh : wa1sh;
    const float* bias  = is2 ? ba2 : ba1;
    float*       outsh = is2 ? at2sh : at1sh;
    float4 bv = *(const float4*)(bias + o4);
    float4 b0 = bv, b1 = bv, b2 = bv;
    const float* e0p = opsh + (op0_ + 0) * 48;
    const float* e1p = opsh + (op0_ + 1) * 48;
    const float* e2p = opsh + (op0_ + 2) * 48;
    #pragma unroll
    for (int h4 = 0; h4 < 12; ++h4) {
      float4 e0 = *(const float4*)(e0p + h4 * 4);
      float4 e1 = *(const float4*)(e1p + h4 * 4);
      float4 e2 = *(const float4*)(e2p + h4 * 4);
      #pragma unroll
      for (int j = 0; j < 4; ++j) {
        float4 wv = *(const float4*)(wsh_ + (h4 * 4 + j) * 128 + o4);
        float s0 = COMP4(e0, j), s1_ = COMP4(e1, j), s2 = COMP4(e2, j);
        b0.x += s0 * wv.x; b0.y += s0 * wv.y; b0.z += s0 * wv.z; b0.w += s0 * wv.w;
        b1.x += s1_ * wv.x; b1.y += s1_ * wv.y; b1.z += s1_ * wv.z; b1.w += s1_ * wv.w;
        b2.x += s2 * wv.x; b2.y += s2 * wv.y; b2.z += s2 * wv.z; b2.w += s2 * wv.w;
      }
    }
    b0 = make_float4(sigmoidf_(b0.x), sigmoidf_(b0.y), sigmoidf_(b0.z), sigmoidf_(b0.w));
    b1 = make_float4(sigmoidf_(b1.x), sigmoidf_(b1.y), sigmoidf_(b1.z), sigmoidf_(b1.w));
    b2 = make_float4(sigmoidf_(b2.x), sigmoidf_(b2.y), sigmoidf_(b2.z), sigmoidf_(b2.w));
    *(float4*)(outsh + (op0_ + 0) * 128 + o4) = b0;
    *(float4*)(outsh + (op0_ + 1) * 128 + o4) = b1;
    *(float4*)(outsh + (op0_ + 2) * 128 + o4) = b2;
    if (is2 && blockIdx.x == 0) {   // publish at2 once (gather reads it)
      *(float4*)(ws + WS_AT2F + (op0_ + 0) * 128 + o4) = b0;
      *(float4*)(ws + WS_AT2F + (op0_ + 1) * 128 + o4) = b1;
      *(float4*)(ws + WS_AT2F + (op0_ + 2) * 128 + o4) = b2;
    }
  } else if (t >= 320 && t < 448) {
    // zero op-0 rows (op==NONE is masked to exactly 0)
    const int u = t - 320;   // 0..127
    at1sh[u] = 0.f;
    at2sh[u] = 0.f;
    if (blockIdx.x == 0) ws[WS_AT2F + u] = 0.f;
  }
  __syncthreads();

  // ---- region B: s1 only (t<192), thread = (2 ci) x (4 o) tile ----
  if (t < 192) {
    const int ci2 = t >> 5, o4 = (t & 31) << 2;
    const float* yA = y0sh + (2 * ci2) * 48;
    const float* yB = yA + 48;
    float4 a0 = make_float4(0.f, 0.f, 0.f, 0.f);
    float4 a1 = make_float4(0.f, 0.f, 0.f, 0.f);
    #pragma unroll
    for (int h4 = 0; h4 < 12; ++h4) {
      float4 ya = *(const float4*)(yA + h4 * 4);
      float4 yb = *(const float4*)(yB + h4 * 4);
      #pragma unroll
      for (int j = 0; j < 4; ++j) {
        float4 wv = *(const float4*)(w1_sh + (h4 * 4 + j) * 128 + o4);
        float sa = COMP4(ya, j), sb = COMP4(yb, j);
        a0.x += sa * wv.x; a0.y += sa * wv.y; a0.z += sa * wv.z; a0.w += sa * wv.w;
        a1.x += sb * wv.x; a1.y += sb * wv.y; a1.z += sb * wv.z; a1.w += sb * wv.w;
      }
    }
    *(float4*)(s1sh + (2 * ci2) * 128 + o4)     = a0;
    *(float4*)(s1sh + (2 * ci2 + 1) * 128 + o4) = a1;
  }
  __syncthreads();                    // wa1sh readers done -> y1 overlay ok

  // ---- step 6: wave w -> 3 configs, y1 rows into wa1sh[w*384 ..] ----
  const int w  = t >> 6, o2 = t & 63;          // w in [0,8)
  const int cfg0 = blockIdx.x * 24 + w * 3;    // up to 5303; tail guarded
  const float2* s1f = (const float2*)s1sh;     // [12][64]
  const float2* a1f = (const float2*)at1sh;    // [7][64]
  float* y1p = wa1sh + w * 384;                // [3 configs][128]

  #pragma unroll
  for (int r = 0; r < 3; ++r) {
    int cfg = cfg0 + r;
    float2 v;
    if (cfg < NCFG_REAL) {
      int c = cfg / CPER, q = cfg % CPER;
      int i, b;
      if (q < 196)       { i = 2; b = 0; }
      else if (q < 637)  { i = 3; b = 196; }
      else if (q < 1421) { i = 4; b = 637; }
      else               { i = 5; b = 1421; }
      q -= b;
      int op2_ = q % 7; q /= 7;
      int f2_  = q % i; q /= i;
      int op1_ = q % 7;
      int f1_  = q / 7;
      int cb = c * 384;
      v = s1f[cb + i * 64 + o2];
      float2 A0 = a1f[op1_ * 64 + o2], B0 = s1f[cb + f1_ * 64 + o2];
      float2 A1 = a1f[op2_ * 64 + o2], B1 = s1f[cb + f2_ * 64 + o2];
      v.x += A0.x * B0.x + A1.x * B1.x;
      v.y += A0.y * B0.y + A1.y * B1.y;
    } else if (cfg < NCFG) {           // init node pseudo-config (no in-edges)
      int j = cfg - NCFG_REAL, c = j >> 1, i = j & 1;
      v = s1f[c * 384 + i * 64 + o2];
    } else {                           // tail slot (block 220 only)
      v = make_float2(0.f, 0.f);
    }
    ((float2*)(y1p + r * 128))[o2] =
        make_float2(fmaxf(v.x, 0.f), fmaxf(v.y, 0.f));
  }
  __syncthreads();

  // ---- step 7: tab rows = y1 @ W2 -- scalar-accumulator gemm, 3 configs ----
  const float2* W2f = (const float2*)W2;
  float ax0 = 0, ax1 = 0, ax2 = 0;
  float ay0 = 0, ay1 = 0, ay2 = 0;

  for (int h = 0; h < 128; h += 4) {
    float4 q0 = *(const float4*)(y1p + 0 * 128 + h);  // wave-broadcast LDS
    float4 q1 = *(const float4*)(y1p + 1 * 128 + h);
    float4 q2 = *(const float4*)(y1p + 2 * 128 + h);
    #pragma unroll
    for (int j = 0; j < 4; ++j) {
      float2 wf = W2f[(h + j) * 64 + o2];
      float w0 = wf.x, w1 = wf.y, y;
      y = COMP4(q0, j); ax0 += y * w0; ay0 += y * w1;
      y = COMP4(q1, j); ax1 += y * w0; ay1 += y * w1;
      y = COMP4(q2, j); ax2 += y * w0; ay2 += y * w1;
    }
  }

  float2* tab = (float2*)(ws + WS_TAB);
  if (cfg0 + 0 < NCFG) tab[(cfg0 + 0) * 64 + o2] = make_float2(ax0, ay0);
  if (cfg0 + 1 < NCFG) tab[(cfg0 + 1) * 64 + o2] = make_float2(ax1, ay1);
  if (cfg0 + 2 < NCFG) tab[(cfg0 + 2) * 64 + o2] = make_float2(ax2, ay2);
}

// 512 blocks x 256 threads; 16 pairs per block (R15-phase-2-verified loop).
__global__ __launch_bounds__(256) void gather_kernel(
    const int* __restrict__ archs, const float* __restrict__ ws,
    float* __restrict__ out)
{
  const int t = threadIdx.x;
  __shared__ int archsh[256];
  archsh[t] = archs[blockIdx.x * 256 + t];   // 512*256 = 8192*16 exact
  __syncthreads();

  const int pp = t >> 6;
  const int o2 = t & 63;
  // P = blockIdx.x*16 + g4*4 + pp; 16 and 4 even -> c = P&1 = pp&1,
  // constant over g4: hoist S0/S1 (init pseudo-rows) out of the loop.
  const int c = pp & 1;

  const float2* tab = (const float2*)(ws + WS_TAB);
  const float2* a2f = (const float2*)(ws + WS_AT2F);

  const float2 S0 = tab[(NCFG_REAL + c * 2 + 0) * 64 + o2];
  const float2 S1 = tab[(NCFG_REAL + c * 2 + 1) * 64 + o2];

  #pragma unroll
  for (int g4 = 0; g4 < 4; ++g4) {
    const int P    = blockIdx.x * 16 + g4 * 4 + pp;
    const int base = g4 * 64 + pp * 16;

    int f[8], op[8];
    #pragma unroll
    for (int e = 0; e < 8; ++e) { f[e] = archsh[base + e]; op[e] = archsh[base + 8 + e]; }

    float2 S2, S3, S4, S5;
    {
      const int ib[4] = {0, 196, 637, 1421};
      #pragma unroll
      for (int i = 2; i < 6; ++i) {
        int e0 = 2 * (i - 2), e1 = e0 + 1;
        int cid = c * CPER + ib[i - 2] +
                  ((f[e0] * 7 + op[e0]) * i + f[e1]) * 7 + op[e1];
        float2 v = tab[cid * 64 + o2];
        if (i == 2) S2 = v; else if (i == 3) S3 = v;
        else if (i == 4) S4 = v; else S5 = v;
      }
    }
    float2 A2[8];
    #pragma unroll
    for (int e = 0; e < 8; ++e) A2[e] = a2f[op[e] * 64 + o2];

    float r0 = S2.x + S3.x + S4.x + S5.x;
    float r1 = S2.y + S3.y + S4.y + S5.y;
    #pragma unroll
    for (int e = 0; e < 8; ++e) {
      int fe = f[e];
      float sx, sy;
      if (fe == 0)      { sx = S0.x; sy = S0.y; }
      else if (fe == 1) { sx = S1.x; sy = S1.y; }
      else if (fe == 2) { sx = S2.x; sy = S2.y; }
      else if (fe == 3) { sx = S3.x; sy = S3.y; }
      else              { sx = S4.x; sy = S4.y; }
      r0 += A2[e].x * sx;
      r1 += A2[e].y * sy;
    }
    ((float2*)out)[P * 64 + o2] = make_float2(r0 * 0.25f, r1 * 0.25f);
  }
}

// ===================== FALLBACK: R9 verbatim (if ws too small) ============
#define FB_S1   0
#define FB_AT1  1536
#define FB_AT2  2432
#define FB_S2I  3328

__global__ __launch_bounds__(512) void precompute_kernel(
    const float* __restrict__ init_emb, const float* __restrict__ other_emb,
    const float* __restrict__ op_embs,  const float* __restrict__ Wx,
    const float* __restrict__ bx,       const float* __restrict__ W1,
    const float* __restrict__ Wa1,      const float* __restrict__ ba1,
    const float* __restrict__ W2,       const float* __restrict__ Wa2,
    const float* __restrict__ ba2,      float* __restrict__ ws)
{
  const int t   = threadIdx.x;
  const int blk = blockIdx.x;
  __shared__ float y0[576];
  __shared__ float s1sh[1536];
  for (int idx = t; idx < 576; idx += 512) {
    int c = idx / 288, i = (idx / 48) % 6, h = idx % 48;
    const float* nptr = (i < 2) ? (init_emb + (c * 2 + i) * 48)
                                : (other_emb + c * 48);
    float acc = bx[h];
    for (int d = 0; d < 48; ++d) acc += nptr[d] * Wx[d * 48 + h];
    y0[idx] = acc;
  }
  __syncthreads();
  for (int idx = t; idx < 1536; idx += 512) {
    int ci = idx >> 7, o = idx & 127;
    const float* yp = y0 + ci * 48;
    float acc = 0.f;
    for (int h = 0; h < 48; ++h) acc += yp[h] * W1[h * 128 + o];
    s1sh[idx] = acc;
    ws[FB_S1 + idx] = acc;
  }
  for (int idx = blk * 112 + t; idx < (blk + 1) * 112; idx += 512) {
    int op = idx >> 7, o = idx & 127;
    float a1 = ba1[o], a2 = ba2[o];
    for (int d = 0; d < 48; ++d) {
      float e = op_embs[op * 48 + d];
      a1 += e * Wa1[d * 128 + o];
      a2 += e * Wa2[d * 128 + o];
    }
    ws[FB_AT1 + idx] = (op == 0) ? 0.f : sigmoidf_(a1);
    ws[FB_AT2 + idx] = (op == 0) ? 0.f : sigmoidf_(a2);
  }
  __syncthreads();
  for (int idx = blk * 64 + t; idx < (blk + 1) * 64; idx += 512) {
    int c = idx >> 8, i = (idx >> 7) & 1, o = idx & 127;
    const float* sp = s1sh + (c * 6 + i) * 128;
    float acc = 0.f;
    for (int h = 0; h < 128; ++h) acc += fmaxf(sp[h], 0.f) * W2[h * 128 + o];
    ws[FB_S2I + idx] = acc;
  }
}

__global__ __launch_bounds__(256) void main_kernel(
    const int* __restrict__ archs, const float* __restrict__ W2,
    const float* __restrict__ ws, float* __restrict__ out)
{
  const int t  = threadIdx.x;
  const int pp = t >> 6;
  const int o2 = t & 63;
  const int P  = blockIdx.x * 4 + pp;
  const int c  = P & 1;
  __shared__ float y1sh[4][512];
  __shared__ int   archsh[64];
  if (t < 64) archsh[t] = archs[blockIdx.x * 64 + t];
  __syncthreads();
  int f[8], op[8];
  #pragma unroll
  for (int e = 0; e < 8; ++e) { f[e] = archsh[pp * 16 + e]; op[e] = archsh[pp * 16 + 8 + e]; }
  const float2* s1p = (const float2*)ws + c * 384;
  const float2* at1 = (const float2*)(ws + FB_AT1);
  const float2* at2 = (const float2*)(ws + FB_AT2);
  const float2* s2i = (const float2*)(ws + FB_S2I) + c * 128;
  float2 A2[8];
  #pragma unroll
  for (int e = 0; e < 8; ++e) A2[e] = at2[op[e] * 64 + o2];
  float2 S0 = s2i[o2], S1 = s2i[64 + o2];
  #pragma unroll
  for (int i = 0; i < 4; ++i) {
    float2 v = s1p[(2 + i) * 64 + o2];
    int e0 = 2 * i, e1 = 2 * i + 1;
    float2 A0 = at1[op[e0] * 64 + o2];
    float2 B0 = s1p[f[e0] * 64 + o2];
    float2 A1 = at1[op[e1] * 64 + o2];
    float2 B1 = s1p[f[e1] * 64 + o2];
    v.x += A0.x * B0.x + A1.x * B1.x;
    v.y += A0.y * B0.y + A1.y * B1.y;
    ((float2*)(y1sh[pp] + i * 128))[o2] =
        make_float2(fmaxf(v.x, 0.f), fmaxf(v.y, 0.f));
  }
  __syncthreads();
  const float* y1p = y1sh[pp];
  const float2* W2f = (const float2*)W2;
  float ax0 = 0, ax1 = 0, ax2 = 0, ax3 = 0;
  float ay0 = 0, ay1 = 0, ay2 = 0, ay3 = 0;
  for (int h = 0; h < 128; h += 4) {
    float4 q0 = *(const float4*)(y1p + 0 * 128 + h);
    float4 q1 = *(const float4*)(y1p + 1 * 128 + h);
    float4 q2 = *(const float4*)(y1p + 2 * 128 + h);
    float4 q3 = *(const float4*)(y1p + 3 * 128 + h);
    #pragma unroll
    for (int j = 0; j < 4; ++j) {
      float2 wf = W2f[(h + j) * 64 + o2];
      float w0 = wf.x, w1 = wf.y, y;
      y = COMP4(q0, j); ax0 += y * w0; ay0 += y * w1;
      y = COMP4(q1, j); ax1 += y * w0; ay1 += y * w1;
      y = COMP4(q2, j); ax2 += y * w0; ay2 += y * w1;
      y = COMP4(q3, j); ax3 += y * w0; ay3 += y * w1;
    }
  }
  float r0 = ax0 + ax1 + ax2 + ax3;
  float r1 = ay0 + ay1 + ay2 + ay3;
  #pragma unroll
  for (int e = 0; e < 8; ++e) {
    int fe = f[e];
    float sx, sy;
    if (fe == 0)      { sx = S0.x; sy = S0.y; }
    else if (fe == 1) { sx = S1.x; sy = S1.y; }
    else if (fe == 2) { sx = ax0; sy = ay0; }
    else if (fe == 3) { sx = ax1; sy = ay1; }
    else if (fe == 4) { sx = ax2; sy = ay2; }
    else              { sx = ax3; sy = ay3; }
    r0 += A2[e].x * sx;
    r1 += A2[e].y * sy;
  }
  ((float2*)out)[P * 64 + o2] = make_float2(r0 * 0.25f, r1 * 0.25f);
}

extern "C" void kernel_launch(void* const* d_in, const int* in_sizes, int n_in,
                              void* d_out, int out_size, void* d_ws, size_t ws_size,
                              hipStream_t stream) {
  const int* archs = (const int*)d_in[0];
  float* ws = (float*)d_ws;
  if (ws_size >= WS_NEED) {
    config_kernel<<<NBLK, 512, 0, stream>>>(
        (const float*)d_in[1], (const float*)d_in[2], (const float*)d_in[3],
        (const float*)d_in[4], (const float*)d_in[5], (const float*)d_in[6],
        (const float*)d_in[7], (const float*)d_in[8], (const float*)d_in[9],
        (const float*)d_in[10], (const float*)d_in[11], ws);
    gather_kernel<<<NPAIR / 16, 256, 0, stream>>>(archs, ws, (float*)d_out);
  } else {
    precompute_kernel<<<8, 512, 0, stream>>>(
        (const float*)d_in[1], (const float*)d_in[2], (const float*)d_in[3],
        (const float*)d_in[4], (const float*)d_in[5], (const float*)d_in[6],
        (const float*)d_in[7], (const float*)d_in[8], (const float*)d_in[9],
        (const float*)d_in[10], (const float*)d_in[11], ws);
    main_kernel<<<NPAIR / 4, 256, 0, stream>>>(archs, (const float*)d_in[9], ws,
                                               (float*)d_out);
  }
}

// Round 7
// 99.783 us; speedup vs baseline: 1.0026x; 1.0026x over previous
//
#include <hip/hip_runtime.h>

#define NPAIR 8192   // B*NCG

// ===================== config-deduplicated path =====================
// Node layer-1 output depends only on (c, i, f_s0, op_s0, f_s1, op_s1):
// 5292 real configs + 4 init pseudo-rows = 5296. config_kernel builds
// tab[cfg] = relu(y1_cfg) @ W2; gather_kernel is a pure gather/aggregate.
// R14: scalar/compile-time-indexed accumulators only (runtime-indexed
//   register arrays spill to scratch).
// R15: cooperative fusion FAILED (235us). NEVER use cooperative launch here.
// R16 FAILED (127us): narrow strided global loads latency-exposed.
// R17 (104us): stage ALL weights at t0 (one ~86KB burst), fuse s1|at1|at2.
// R18 (100.8us): 512 thr; step 3 was LDS-BW-bound (LDS BW is per-CU).
// R19 (98.3us): 2-D register blocking + b128 LDS reads everywhere.  <= BEST
// R20 (100.0us, NEUTRAL): phase rebalance + 512x16 gather both within-noise
//   regressions -> reverted. Controllable budget (~15us) exhausted: total is
//   ~82-84us harness poison-fills (HBM-roofline themselves) + config ~9 +
//   gather ~6. This file == R19 logic exactly.
#define NCFG_REAL 5292
#define NCFG      5296
#define CPER      2646
#define NBLK      221       // <= 256: single wave of blocks, no tail round
#define WS_AT2F   0         // at2 table [7][128] (row 0 zeroed)
#define WS_TAB    1024      // tab [NCFG][128]
#define WS_NEED   ((size_t)(1024 + NCFG * 128) * 4)

#define COMP4(v, j) ((j) == 0 ? (v).x : (j) == 1 ? (v).y : (j) == 2 ? (v).z : (v).w)

__device__ __forceinline__ float sigmoidf_(float x) {
  return 1.0f / (1.0f + __expf(-x));
}

// 221 blocks x 512 threads; 24 configs per block, 3 per wave.
__global__ __launch_bounds__(512) void config_kernel(
    const float* __restrict__ init_emb, const float* __restrict__ other_emb,
    const float* __restrict__ op_embs,  const float* __restrict__ Wx,
    const float* __restrict__ bx,       const float* __restrict__ W1,
    const float* __restrict__ Wa1,      const float* __restrict__ ba1,
    const float* __restrict__ W2,       const float* __restrict__ Wa2,
    const float* __restrict__ ba2,      float* __restrict__ ws)
{
  __shared__ __align__(16) float wx_sh[2304];   // Wx 48x48
  __shared__ __align__(16) float w1_sh[6144];   // W1 48x128
  __shared__ __align__(16) float wa1sh[6144];   // Wa1 48x128; later y1 overlay
  __shared__ __align__(16) float wa2sh[6144];   // Wa2 48x128
  __shared__ __align__(16) float s1sh[1536];    // support1 [2][6][128]
  __shared__ __align__(16) float at1sh[896];    // sigmoid(a1) [7][128] row0=0
  __shared__ __align__(16) float at2sh[896];    // sigmoid(a2) [7][128] row0=0
  __shared__ __align__(16) float y0sh[576];     // y0 [2][6][48]
  __shared__ __align__(16) float embsh[336];    // init(192) other(96) bx(48)
  __shared__ __align__(16) float opsh[336];     // op_embs [7][48]
  const int t = threadIdx.x;

  // ---- step 1: stage EVERYTHING (one wide burst, single wait) ----
  for (int i = t; i < 576; i += 512)  ((float4*)wx_sh)[i] = ((const float4*)Wx)[i];
  for (int i = t; i < 1536; i += 512) ((float4*)w1_sh)[i] = ((const float4*)W1)[i];
  for (int i = t; i < 1536; i += 512) ((float4*)wa1sh)[i] = ((const float4*)Wa1)[i];
  for (int i = t; i < 1536; i += 512) ((float4*)wa2sh)[i] = ((const float4*)Wa2)[i];
  if (t < 48)        ((float4*)embsh)[t]     = ((const float4*)init_emb)[t];
  else if (t < 72)   ((float4*)embsh)[t]     = ((const float4*)other_emb)[t - 48];
  else if (t < 84)   ((float4*)embsh)[t]     = ((const float4*)bx)[t - 72];
  else if (t < 168)  ((float4*)opsh)[t - 84] = ((const float4*)op_embs)[t - 84];
  __syncthreads();

  // ---- step 2: y0[r][h] = node @ Wx + bx, all-b128 LDS reads ----
  // 144 threads: r = t/12 (row 0..11), h4 = t%12 (float4 along h).
  if (t < 144) {
    const int r = t / 12, h4 = t - r * 12;
    const int c = r / 6, i = r - c * 6;
    const float* nptr = (i < 2) ? (embsh + (c * 2 + i) * 48)
                                : (embsh + 192 + c * 48);
    float4 acc = *(const float4*)(embsh + 288 + h4 * 4);   // bx
    #pragma unroll
    for (int d4 = 0; d4 < 12; ++d4) {
      float4 nv = *(const float4*)(nptr + d4 * 4);
      #pragma unroll
      for (int j = 0; j < 4; ++j) {
        float4 wv = *(const float4*)(wx_sh + (d4 * 4 + j) * 48 + h4 * 4);
        float s = COMP4(nv, j);
        acc.x += s * wv.x; acc.y += s * wv.y;
        acc.z += s * wv.z; acc.w += s * wv.w;
      }
    }
    *(float4*)(y0sh + r * 48 + h4 * 4) = acc;
  }
  __syncthreads();

  // ---- step 3: register-blocked s1 | at1 | at2 (all-b128 LDS reads) ----
  // Role by wave-aligned tid range: [0,192) s1, [192,256) at1, [256,320) at2,
  // [320,448) zero op-0 rows. W values reused across ci/op rows in registers.
  if (t < 192) {
    // s1: thread = (2 ci) x (4 o) tile. ci2 = t>>5 in [0,6), o4 = (t&31)*4.
    const int ci2 = t >> 5, o4 = (t & 31) << 2;
    const float* yA = y0sh + (2 * ci2) * 48;
    const float* yB = yA + 48;
    float4 a0 = make_float4(0.f, 0.f, 0.f, 0.f);
    float4 a1 = make_float4(0.f, 0.f, 0.f, 0.f);
    #pragma unroll
    for (int h4 = 0; h4 < 12; ++h4) {
      float4 ya = *(const float4*)(yA + h4 * 4);
      float4 yb = *(const float4*)(yB + h4 * 4);
      #pragma unroll
      for (int j = 0; j < 4; ++j) {
        float4 wv = *(const float4*)(w1_sh + (h4 * 4 + j) * 128 + o4);
        float sa = COMP4(ya, j), sb = COMP4(yb, j);
        a0.x += sa * wv.x; a0.y += sa * wv.y; a0.z += sa * wv.z; a0.w += sa * wv.w;
        a1.x += sb * wv.x; a1.y += sb * wv.y; a1.z += sb * wv.z; a1.w += sb * wv.w;
      }
    }
    *(float4*)(s1sh + (2 * ci2) * 128 + o4)     = a0;
    *(float4*)(s1sh + (2 * ci2 + 1) * 128 + o4) = a1;
  } else if (t < 320) {
    // at1/at2: thread = (3 op) x (4 o). ops {1,2,3} or {4,5,6}; op0 zeroed below.
    const int is2  = (t >= 256);
    const int u    = t - (is2 ? 256 : 192);
    const int half = u >> 5, o4 = (u & 31) << 2;
    const int op0_ = 1 + 3 * half;
    const float* wsh_  = is2 ? wa2sh : wa1sh;
    const float* bias  = is2 ? ba2 : ba1;
    float*       outsh = is2 ? at2sh : at1sh;
    float4 bv = *(const float4*)(bias + o4);
    float4 b0 = bv, b1 = bv, b2 = bv;
    const float* e0p = opsh + (op0_ + 0) * 48;
    const float* e1p = opsh + (op0_ + 1) * 48;
    const float* e2p = opsh + (op0_ + 2) * 48;
    #pragma unroll
    for (int h4 = 0; h4 < 12; ++h4) {
      float4 e0 = *(const float4*)(e0p + h4 * 4);
      float4 e1 = *(const float4*)(e1p + h4 * 4);
      float4 e2 = *(const float4*)(e2p + h4 * 4);
      #pragma unroll
      for (int j = 0; j < 4; ++j) {
        float4 wv = *(const float4*)(wsh_ + (h4 * 4 + j) * 128 + o4);
        float s0 = COMP4(e0, j), s1_ = COMP4(e1, j), s2 = COMP4(e2, j);
        b0.x += s0 * wv.x; b0.y += s0 * wv.y; b0.z += s0 * wv.z; b0.w += s0 * wv.w;
        b1.x += s1_ * wv.x; b1.y += s1_ * wv.y; b1.z += s1_ * wv.z; b1.w += s1_ * wv.w;
        b2.x += s2 * wv.x; b2.y += s2 * wv.y; b2.z += s2 * wv.z; b2.w += s2 * wv.w;
      }
    }
    b0 = make_float4(sigmoidf_(b0.x), sigmoidf_(b0.y), sigmoidf_(b0.z), sigmoidf_(b0.w));
    b1 = make_float4(sigmoidf_(b1.x), sigmoidf_(b1.y), sigmoidf_(b1.z), sigmoidf_(b1.w));
    b2 = make_float4(sigmoidf_(b2.x), sigmoidf_(b2.y), sigmoidf_(b2.z), sigmoidf_(b2.w));
    *(float4*)(outsh + (op0_ + 0) * 128 + o4) = b0;
    *(float4*)(outsh + (op0_ + 1) * 128 + o4) = b1;
    *(float4*)(outsh + (op0_ + 2) * 128 + o4) = b2;
    if (is2 && blockIdx.x == 0) {   // publish at2 once (gather reads it)
      *(float4*)(ws + WS_AT2F + (op0_ + 0) * 128 + o4) = b0;
      *(float4*)(ws + WS_AT2F + (op0_ + 1) * 128 + o4) = b1;
      *(float4*)(ws + WS_AT2F + (op0_ + 2) * 128 + o4) = b2;
    }
  } else if (t < 448) {
    // zero op-0 rows (op==NONE is masked to exactly 0)
    const int u = t - 320;   // 0..127
    at1sh[u] = 0.f;
    at2sh[u] = 0.f;
    if (blockIdx.x == 0) ws[WS_AT2F + u] = 0.f;
  }
  __syncthreads();                    // wa1sh readers done -> y1 overlay ok

  // ---- step 6: wave w -> 3 configs, y1 rows into wa1sh[w*384 ..] ----
  const int w  = t >> 6, o2 = t & 63;          // w in [0,8)
  const int cfg0 = blockIdx.x * 24 + w * 3;    // up to 5303; tail guarded
  const float2* s1f = (const float2*)s1sh;     // [12][64]
  const float2* a1f = (const float2*)at1sh;    // [7][64]
  float* y1p = wa1sh + w * 384;                // [3 configs][128]

  #pragma unroll
  for (int r = 0; r < 3; ++r) {
    int cfg = cfg0 + r;
    float2 v;
    if (cfg < NCFG_REAL) {
      int c = cfg / CPER, q = cfg % CPER;
      int i, b;
      if (q < 196)       { i = 2; b = 0; }
      else if (q < 637)  { i = 3; b = 196; }
      else if (q < 1421) { i = 4; b = 637; }
      else               { i = 5; b = 1421; }
      q -= b;
      int op2_ = q % 7; q /= 7;
      int f2_  = q % i; q /= i;
      int op1_ = q % 7;
      int f1_  = q / 7;
      int cb = c * 384;
      v = s1f[cb + i * 64 + o2];
      float2 A0 = a1f[op1_ * 64 + o2], B0 = s1f[cb + f1_ * 64 + o2];
      float2 A1 = a1f[op2_ * 64 + o2], B1 = s1f[cb + f2_ * 64 + o2];
      v.x += A0.x * B0.x + A1.x * B1.x;
      v.y += A0.y * B0.y + A1.y * B1.y;
    } else if (cfg < NCFG) {           // init node pseudo-config (no in-edges)
      int j = cfg - NCFG_REAL, c = j >> 1, i = j & 1;
      v = s1f[c * 384 + i * 64 + o2];
    } else {                           // tail slot (block 220 only)
      v = make_float2(0.f, 0.f);
    }
    ((float2*)(y1p + r * 128))[o2] =
        make_float2(fmaxf(v.x, 0.f), fmaxf(v.y, 0.f));
  }
  __syncthreads();

  // ---- step 7: tab rows = y1 @ W2 -- scalar-accumulator gemm, 3 configs ----
  const float2* W2f = (const float2*)W2;
  float ax0 = 0, ax1 = 0, ax2 = 0;
  float ay0 = 0, ay1 = 0, ay2 = 0;

  for (int h = 0; h < 128; h += 4) {
    float4 q0 = *(const float4*)(y1p + 0 * 128 + h);  // wave-broadcast LDS
    float4 q1 = *(const float4*)(y1p + 1 * 128 + h);
    float4 q2 = *(const float4*)(y1p + 2 * 128 + h);
    #pragma unroll
    for (int j = 0; j < 4; ++j) {
      float2 wf = W2f[(h + j) * 64 + o2];
      float w0 = wf.x, w1 = wf.y, y;
      y = COMP4(q0, j); ax0 += y * w0; ay0 += y * w1;
      y = COMP4(q1, j); ax1 += y * w0; ay1 += y * w1;
      y = COMP4(q2, j); ax2 += y * w0; ay2 += y * w1;
    }
  }

  float2* tab = (float2*)(ws + WS_TAB);
  if (cfg0 + 0 < NCFG) tab[(cfg0 + 0) * 64 + o2] = make_float2(ax0, ay0);
  if (cfg0 + 1 < NCFG) tab[(cfg0 + 1) * 64 + o2] = make_float2(ax1, ay1);
  if (cfg0 + 2 < NCFG) tab[(cfg0 + 2) * 64 + o2] = make_float2(ax2, ay2);
}

// 2048 blocks x 256 threads; 4 pairs per block (R19 best-measured shape).
__global__ __launch_bounds__(256) void gather_kernel(
    const int* __restrict__ archs, const float* __restrict__ ws,
    float* __restrict__ out)
{
  const int t  = threadIdx.x;
  const int pp = t >> 6;
  const int o2 = t & 63;
  const int P  = blockIdx.x * 4 + pp;
  const int c  = P & 1;

  __shared__ int archsh[64];
  if (t < 64) archsh[t] = archs[blockIdx.x * 64 + t];
  __syncthreads();

  int f[8], op[8];
  #pragma unroll
  for (int e = 0; e < 8; ++e) { f[e] = archsh[pp * 16 + e]; op[e] = archsh[pp * 16 + 8 + e]; }

  const float2* tab = (const float2*)(ws + WS_TAB);
  const float2* a2f = (const float2*)(ws + WS_AT2F);

  float2 S0 = tab[(NCFG_REAL + c * 2 + 0) * 64 + o2];
  float2 S1 = tab[(NCFG_REAL + c * 2 + 1) * 64 + o2];
  float2 S2, S3, S4, S5;
  {
    const int ib[4] = {0, 196, 637, 1421};
    #pragma unroll
    for (int i = 2; i < 6; ++i) {
      int e0 = 2 * (i - 2), e1 = e0 + 1;
      int cid = c * CPER + ib[i - 2] +
                ((f[e0] * 7 + op[e0]) * i + f[e1]) * 7 + op[e1];
      float2 v = tab[cid * 64 + o2];
      if (i == 2) S2 = v; else if (i == 3) S3 = v;
      else if (i == 4) S4 = v; else S5 = v;
    }
  }
  float2 A2[8];
  #pragma unroll
  for (int e = 0; e < 8; ++e) A2[e] = a2f[op[e] * 64 + o2];

  float r0 = S2.x + S3.x + S4.x + S5.x;
  float r1 = S2.y + S3.y + S4.y + S5.y;
  #pragma unroll
  for (int e = 0; e < 8; ++e) {
    int fe = f[e];
    float sx, sy;
    if (fe == 0)      { sx = S0.x; sy = S0.y; }
    else if (fe == 1) { sx = S1.x; sy = S1.y; }
    else if (fe == 2) { sx = S2.x; sy = S2.y; }
    else if (fe == 3) { sx = S3.x; sy = S3.y; }
    else              { sx = S4.x; sy = S4.y; }
    r0 += A2[e].x * sx;
    r1 += A2[e].y * sy;
  }
  ((float2*)out)[P * 64 + o2] = make_float2(r0 * 0.25f, r1 * 0.25f);
}

// ===================== FALLBACK: R9 verbatim (if ws too small) ============
#define FB_S1   0
#define FB_AT1  1536
#define FB_AT2  2432
#define FB_S2I  3328

__global__ __launch_bounds__(512) void precompute_kernel(
    const float* __restrict__ init_emb, const float* __restrict__ other_emb,
    const float* __restrict__ op_embs,  const float* __restrict__ Wx,
    const float* __restrict__ bx,       const float* __restrict__ W1,
    const float* __restrict__ Wa1,      const float* __restrict__ ba1,
    const float* __restrict__ W2,       const float* __restrict__ Wa2,
    const float* __restrict__ ba2,      float* __restrict__ ws)
{
  const int t   = threadIdx.x;
  const int blk = blockIdx.x;
  __shared__ float y0[576];
  __shared__ float s1sh[1536];
  for (int idx = t; idx < 576; idx += 512) {
    int c = idx / 288, i = (idx / 48) % 6, h = idx % 48;
    const float* nptr = (i < 2) ? (init_emb + (c * 2 + i) * 48)
                                : (other_emb + c * 48);
    float acc = bx[h];
    for (int d = 0; d < 48; ++d) acc += nptr[d] * Wx[d * 48 + h];
    y0[idx] = acc;
  }
  __syncthreads();
  for (int idx = t; idx < 1536; idx += 512) {
    int ci = idx >> 7, o = idx & 127;
    const float* yp = y0 + ci * 48;
    float acc = 0.f;
    for (int h = 0; h < 48; ++h) acc += yp[h] * W1[h * 128 + o];
    s1sh[idx] = acc;
    ws[FB_S1 + idx] = acc;
  }
  for (int idx = blk * 112 + t; idx < (blk + 1) * 112; idx += 512) {
    int op = idx >> 7, o = idx & 127;
    float a1 = ba1[o], a2 = ba2[o];
    for (int d = 0; d < 48; ++d) {
      float e = op_embs[op * 48 + d];
      a1 += e * Wa1[d * 128 + o];
      a2 += e * Wa2[d * 128 + o];
    }
    ws[FB_AT1 + idx] = (op == 0) ? 0.f : sigmoidf_(a1);
    ws[FB_AT2 + idx] = (op == 0) ? 0.f : sigmoidf_(a2);
  }
  __syncthreads();
  for (int idx = blk * 64 + t; idx < (blk + 1) * 64; idx += 512) {
    int c = idx >> 8, i = (idx >> 7) & 1, o = idx & 127;
    const float* sp = s1sh + (c * 6 + i) * 128;
    float acc = 0.f;
    for (int h = 0; h < 128; ++h) acc += fmaxf(sp[h], 0.f) * W2[h * 128 + o];
    ws[FB_S2I + idx] = acc;
  }
}

__global__ __launch_bounds__(256) void main_kernel(
    const int* __restrict__ archs, const float* __restrict__ W2,
    const float* __restrict__ ws, float* __restrict__ out)
{
  const int t  = threadIdx.x;
  const int pp = t >> 6;
  const int o2 = t & 63;
  const int P  = blockIdx.x * 4 + pp;
  const int c  = P & 1;
  __shared__ float y1sh[4][512];
  __shared__ int   archsh[64];
  if (t < 64) archsh[t] = archs[blockIdx.x * 64 + t];
  __syncthreads();
  int f[8], op[8];
  #pragma unroll
  for (int e = 0; e < 8; ++e) { f[e] = archsh[pp * 16 + e]; op[e] = archsh[pp * 16 + 8 + e]; }
  const float2* s1p = (const float2*)ws + c * 384;
  const float2* at1 = (const float2*)(ws + FB_AT1);
  const float2* at2 = (const float2*)(ws + FB_AT2);
  const float2* s2i = (const float2*)(ws + FB_S2I) + c * 128;
  float2 A2[8];
  #pragma unroll
  for (int e = 0; e < 8; ++e) A2[e] = at2[op[e] * 64 + o2];
  float2 S0 = s2i[o2], S1 = s2i[64 + o2];
  #pragma unroll
  for (int i = 0; i < 4; ++i) {
    float2 v = s1p[(2 + i) * 64 + o2];
    int e0 = 2 * i, e1 = 2 * i + 1;
    float2 A0 = at1[op[e0] * 64 + o2];
    float2 B0 = s1p[f[e0] * 64 + o2];
    float2 A1 = at1[op[e1] * 64 + o2];
    float2 B1 = s1p[f[e1] * 64 + o2];
    v.x += A0.x * B0.x + A1.x * B1.x;
    v.y += A0.y * B0.y + A1.y * B1.y;
    ((float2*)(y1sh[pp] + i * 128))[o2] =
        make_float2(fmaxf(v.x, 0.f), fmaxf(v.y, 0.f));
  }
  __syncthreads();
  const float* y1p = y1sh[pp];
  const float2* W2f = (const float2*)W2;
  float ax0 = 0, ax1 = 0, ax2 = 0, ax3 = 0;
  float ay0 = 0, ay1 = 0, ay2 = 0, ay3 = 0;
  for (int h = 0; h < 128; h += 4) {
    float4 q0 = *(const float4*)(y1p + 0 * 128 + h);
    float4 q1 = *(const float4*)(y1p + 1 * 128 + h);
    float4 q2 = *(const float4*)(y1p + 2 * 128 + h);
    float4 q3 = *(const float4*)(y1p + 3 * 128 + h);
    #pragma unroll
    for (int j = 0; j < 4; ++j) {
      float2 wf = W2f[(h + j) * 64 + o2];
      float w0 = wf.x, w1 = wf.y, y;
      y = COMP4(q0, j); ax0 += y * w0; ay0 += y * w1;
      y = COMP4(q1, j); ax1 += y * w0; ay1 += y * w1;
      y = COMP4(q2, j); ax2 += y * w0; ay2 += y * w1;
      y = COMP4(q3, j); ax3 += y * w0; ay3 += y * w1;
    }
  }
  float r0 = ax0 + ax1 + ax2 + ax3;
  float r1 = ay0 + ay1 + ay2 + ay3;
  #pragma unroll
  for (int e = 0; e < 8; ++e) {
    int fe = f[e];
    float sx, sy;
    if (fe == 0)      { sx = S0.x; sy = S0.y; }
    else if (fe == 1) { sx = S1.x; sy = S1.y; }
    else if (fe == 2) { sx = ax0; sy = ay0; }
    else if (fe == 3) { sx = ax1; sy = ay1; }
    else if (fe == 4) { sx = ax2; sy = ay2; }
    else              { sx = ax3; sy = ay3; }
    r0 += A2[e].x * sx;
    r1 += A2[e].y * sy;
  }
  ((float2*)out)[P * 64 + o2] = make_float2(r0 * 0.25f, r1 * 0.25f);
}

extern "C" void kernel_launch(void* const* d_in, const int* in_sizes, int n_in,
                              void* d_out, int out_size, void* d_ws, size_t ws_size,
                              hipStream_t stream) {
  const int* archs = (const int*)d_in[0];
  float* ws = (float*)d_ws;
  if (ws_size >= WS_NEED) {
    config_kernel<<<NBLK, 512, 0, stream>>>(
        (const float*)d_in[1], (const float*)d_in[2], (const float*)d_in[3],
        (const float*)d_in[4], (const float*)d_in[5], (const float*)d_in[6],
        (const float*)d_in[7], (const float*)d_in[8], (const float*)d_in[9],
        (const float*)d_in[10], (const float*)d_in[11], ws);
    gather_kernel<<<NPAIR / 4, 256, 0, stream>>>(archs, ws, (float*)d_out);
  } else {
    precompute_kernel<<<8, 512, 0, stream>>>(
        (const float*)d_in[1], (const float*)d_in[2], (const float*)d_in[3],
        (const float*)d_in[4], (const float*)d_in[5], (const float*)d_in[6],
        (const float*)d_in[7], (const float*)d_in[8], (const float*)d_in[9],
        (const float*)d_in[10], (const float*)d_in[11], ws);
    main_kernel<<<NPAIR / 4, 256, 0, stream>>>(archs, (const float*)d_in[9], ws,
                                               (float*)d_out);
  }
}